// Round 2
// baseline (51.559 us; speedup 1.0000x reference)
//
#include <hip/hip_runtime.h>

// QuantizationLoss: sum over all elements of min(1, min_i |x - (i/127.5 - 1)|),
// i in [0,255]. The scan in the reference starts from ones_like(x), so the
// result is capped at 1.0 (matters for |x| > 2 where the nearest level is ±1
// and the distance exceeds 1).
// Levels form a uniform grid on [-1,1] with step 1/127.5, so the min over 256
// levels is the distance to the nearest (clamped) grid point:
//   i = clamp(rint((x+1)*127.5), 0, 255);  dist = min(1, |x - (i/127.5 - 1)|)
// Memory-bound streaming reduction over 134 MB.

#define BLOCK 256

__device__ __forceinline__ float qdist(float x) {
    const float INV_D = 127.5f;          // 1/step
    const float D     = 1.0f / 127.5f;   // step
    float r = rintf((x + 1.0f) * INV_D);
    r = fminf(fmaxf(r, 0.0f), 255.0f);
    float lv = r * D - 1.0f;
    return fminf(fabsf(x - lv), 1.0f);   // scan init = 1.0 caps the min
}

__global__ __launch_bounds__(BLOCK) void QuantizationLoss_kernel(
    const float4* __restrict__ in4, int n4,
    const float* __restrict__ in_tail, int ntail,
    float* __restrict__ out)
{
    int tid    = blockIdx.x * blockDim.x + threadIdx.x;
    int stride = gridDim.x * blockDim.x;

    float acc = 0.0f;

    for (int i = tid; i < n4; i += stride) {
        float4 v = in4[i];
        acc += qdist(v.x);
        acc += qdist(v.y);
        acc += qdist(v.z);
        acc += qdist(v.w);
    }

    // tail elements (n not divisible by 4)
    if (tid < ntail) acc += qdist(in_tail[tid]);

    // wave-level reduction (64 lanes)
    #pragma unroll
    for (int off = 32; off > 0; off >>= 1)
        acc += __shfl_down(acc, off, 64);

    __shared__ float smem[BLOCK / 64];
    int lane = threadIdx.x & 63;
    int wid  = threadIdx.x >> 6;
    if (lane == 0) smem[wid] = acc;
    __syncthreads();

    if (threadIdx.x == 0) {
        float s = 0.0f;
        #pragma unroll
        for (int w = 0; w < BLOCK / 64; ++w) s += smem[w];
        atomicAdd(out, s);
    }
}

extern "C" void kernel_launch(void* const* d_in, const int* in_sizes, int n_in,
                              void* d_out, int out_size, void* d_ws, size_t ws_size,
                              hipStream_t stream) {
    const float* x = (const float*)d_in[0];
    float* out = (float*)d_out;
    int n = in_sizes[0];

    int n4    = n >> 2;
    int ntail = n & 3;
    const float* tail = x + (n4 << 2);

    // d_out is poisoned (0xAA) before timing and NOT re-poisoned between
    // replays; we accumulate with atomics, so zero it every call.
    hipMemsetAsync(d_out, 0, sizeof(float), stream);

    int grid = (n4 + BLOCK - 1) / BLOCK;
    if (grid > 2048) grid = 2048;
    if (grid < 1) grid = 1;

    QuantizationLoss_kernel<<<grid, BLOCK, 0, stream>>>(
        (const float4*)x, n4, tail, ntail, out);
}

// Round 3
// 46.771 us; speedup vs baseline: 1.1024x; 1.1024x over previous
//
#include <hip/hip_runtime.h>

// QuantizationLoss: sum over all elements of min(1, min_i |x - (i/127.5 - 1)|),
// i in [0,255]. Scan init = ones_like caps the distance at 1.0.
// Closed form: nearest level of the uniform grid on [-1,1], step 1/127.5:
//   r = clamp(rint((x+1)*127.5), 0, 255);  dist = min(1, |x - (r/127.5 - 1)|)
// Memory-bound streaming reduction over 134 MB.
//
// Round 2 -> 3: 4x unrolled independent float4 loads per iteration (4
// outstanding global_load_dwordx4 per wave) + 4 accumulators. Round 2's
// single-load loop only sustained ~2.6 TB/s (1 load in flight per wave).

#define BLOCK 256
#define UNROLL 4

__device__ __forceinline__ float qdist(float x) {
    const float INV_D = 127.5f;          // 1/step
    const float D     = 1.0f / 127.5f;   // step
    float r = rintf((x + 1.0f) * INV_D); // fma + rndne
    r = fminf(fmaxf(r, 0.0f), 255.0f);   // med3
    float lv = r * D - 1.0f;             // fma
    return fminf(fabsf(x - lv), 1.0f);   // sub + min(abs(),1.0)
}

__device__ __forceinline__ float qdist4(float4 v) {
    return qdist(v.x) + qdist(v.y) + qdist(v.z) + qdist(v.w);
}

__global__ __launch_bounds__(BLOCK) void QuantizationLoss_kernel(
    const float4* __restrict__ in4, int n4,
    const float* __restrict__ in_tail, int ntail,
    float* __restrict__ out)
{
    const int tid = blockIdx.x * blockDim.x + threadIdx.x;
    const int S   = gridDim.x * blockDim.x;        // stride in float4s
    const int CH  = S * UNROLL;                    // float4s per outer chunk

    float a0 = 0.f, a1 = 0.f, a2 = 0.f, a3 = 0.f;

    // main loop: all UNROLL loads in-bounds (independent, issued back-to-back)
    int i = tid;
    for (; i + (UNROLL - 1) * S < n4; i += CH) {
        float4 v0 = in4[i];
        float4 v1 = in4[i + S];
        float4 v2 = in4[i + 2 * S];
        float4 v3 = in4[i + 3 * S];
        a0 += qdist4(v0);
        a1 += qdist4(v1);
        a2 += qdist4(v2);
        a3 += qdist4(v3);
    }
    // remainder float4s
    for (; i < n4; i += S) a0 += qdist4(in4[i]);

    // tail scalars (n not divisible by 4)
    if (tid < ntail) a0 += qdist(in_tail[tid]);

    float acc = (a0 + a1) + (a2 + a3);

    // wave-level reduction (64 lanes)
    #pragma unroll
    for (int off = 32; off > 0; off >>= 1)
        acc += __shfl_down(acc, off, 64);

    __shared__ float smem[BLOCK / 64];
    int lane = threadIdx.x & 63;
    int wid  = threadIdx.x >> 6;
    if (lane == 0) smem[wid] = acc;
    __syncthreads();

    if (threadIdx.x == 0) {
        float s = 0.0f;
        #pragma unroll
        for (int w = 0; w < BLOCK / 64; ++w) s += smem[w];
        atomicAdd(out, s);
    }
}

extern "C" void kernel_launch(void* const* d_in, const int* in_sizes, int n_in,
                              void* d_out, int out_size, void* d_ws, size_t ws_size,
                              hipStream_t stream) {
    const float* x = (const float*)d_in[0];
    float* out = (float*)d_out;
    int n = in_sizes[0];

    int n4    = n >> 2;
    int ntail = n & 3;
    const float* tail = x + (n4 << 2);

    // d_out is poisoned (0xAA) and NOT re-poisoned between replays; we
    // accumulate with atomics, so zero it every call (async, capture-safe).
    hipMemsetAsync(d_out, 0, sizeof(float), stream);

    int grid = (n4 + BLOCK * UNROLL - 1) / (BLOCK * UNROLL);
    if (grid > 2048) grid = 2048;
    if (grid < 1) grid = 1;

    QuantizationLoss_kernel<<<grid, BLOCK, 0, stream>>>(
        (const float4*)x, n4, tail, ntail, out);
}

// Round 4
// 31.307 us; speedup vs baseline: 1.6469x; 1.4939x over previous
//
#include <hip/hip_runtime.h>

// QuantizationLoss: sum over all elements of min(1, min_i |x - (i/127.5 - 1)|),
// i in [0,255]. Scan init = ones_like caps the distance at 1.0.
// Closed form: nearest level of the uniform grid on [-1,1], step 1/127.5:
//   r = clamp(rint((x+1)*127.5), 0, 255);  dist = min(1, |x - (r/127.5 - 1)|)
//
// Round 3 -> 4: two-stage reduction (block partials -> d_ws, tiny second
// kernel overwrites d_out) removes the 4B memset dispatch AND the 2048
// same-address atomicAdd tail. UNROLL 4 -> 8 (8 dwordx4 in flight/wave),
// grid 2048 -> 1024 so each thread runs 4 full unrolled iterations.

#define BLOCK  256
#define UNROLL 8
#define GRID1  1024   // stage-1 blocks; d_ws holds GRID1 floats (4 KB)

__device__ __forceinline__ float qdist(float x) {
    const float INV_D = 127.5f;
    const float D     = 1.0f / 127.5f;
    float r = rintf(__builtin_fmaf(x, INV_D, INV_D)); // (x+1)*127.5
    r = fminf(fmaxf(r, 0.0f), 255.0f);                // v_med3
    float lv = __builtin_fmaf(r, D, -1.0f);
    return fminf(fabsf(x - lv), 1.0f);                // scan init = 1 caps min
}

__device__ __forceinline__ float qdist4(float4 v) {
    return (qdist(v.x) + qdist(v.y)) + (qdist(v.z) + qdist(v.w));
}

__global__ __launch_bounds__(BLOCK) void ql_partial_kernel(
    const float4* __restrict__ in4, int n4,
    const float* __restrict__ in_tail, int ntail,
    float* __restrict__ partial)
{
    const int tid = blockIdx.x * blockDim.x + threadIdx.x;
    const int S   = gridDim.x * blockDim.x;   // stride in float4s
    const int CH  = S * UNROLL;

    float a[UNROLL];
    #pragma unroll
    for (int u = 0; u < UNROLL; ++u) a[u] = 0.0f;

    int i = tid;
    for (; i + (UNROLL - 1) * S < n4; i += CH) {
        float4 v[UNROLL];
        #pragma unroll
        for (int u = 0; u < UNROLL; ++u) v[u] = in4[i + u * S];  // 8 loads in flight
        #pragma unroll
        for (int u = 0; u < UNROLL; ++u) a[u] += qdist4(v[u]);
    }
    for (; i < n4; i += S) a[0] += qdist4(in4[i]);
    if (tid < ntail) a[0] += qdist(in_tail[tid]);

    float acc = 0.0f;
    #pragma unroll
    for (int u = 0; u < UNROLL; ++u) acc += a[u];

    #pragma unroll
    for (int off = 32; off > 0; off >>= 1)
        acc += __shfl_down(acc, off, 64);

    __shared__ float smem[BLOCK / 64];
    int lane = threadIdx.x & 63;
    int wid  = threadIdx.x >> 6;
    if (lane == 0) smem[wid] = acc;
    __syncthreads();

    if (threadIdx.x == 0) {
        float s = 0.0f;
        #pragma unroll
        for (int w = 0; w < BLOCK / 64; ++w) s += smem[w];
        partial[blockIdx.x] = s;   // plain store, no atomics
    }
}

__global__ __launch_bounds__(BLOCK) void ql_final_kernel(
    const float* __restrict__ partial, int np, float* __restrict__ out)
{
    float acc = 0.0f;
    for (int i = threadIdx.x; i < np; i += BLOCK) acc += partial[i];

    #pragma unroll
    for (int off = 32; off > 0; off >>= 1)
        acc += __shfl_down(acc, off, 64);

    __shared__ float smem[BLOCK / 64];
    int lane = threadIdx.x & 63;
    int wid  = threadIdx.x >> 6;
    if (lane == 0) smem[wid] = acc;
    __syncthreads();

    if (threadIdx.x == 0) {
        float s = 0.0f;
        #pragma unroll
        for (int w = 0; w < BLOCK / 64; ++w) s += smem[w];
        out[0] = s;                // overwrites poison; no memset needed
    }
}

extern "C" void kernel_launch(void* const* d_in, const int* in_sizes, int n_in,
                              void* d_out, int out_size, void* d_ws, size_t ws_size,
                              hipStream_t stream) {
    const float* x = (const float*)d_in[0];
    float* out     = (float*)d_out;
    float* partial = (float*)d_ws;   // GRID1 floats = 4 KB of scratch
    int n = in_sizes[0];

    int n4    = n >> 2;
    int ntail = n & 3;
    const float* tail = x + (n4 << 2);

    ql_partial_kernel<<<GRID1, BLOCK, 0, stream>>>(
        (const float4*)x, n4, tail, ntail, partial);
    ql_final_kernel<<<1, BLOCK, 0, stream>>>(partial, GRID1, out);
}

// Round 5
// 30.063 us; speedup vs baseline: 1.7151x; 1.0414x over previous
//
#include <hip/hip_runtime.h>

// QuantizationLoss: sum over all elements of min(1, min_i |x - (i/127.5 - 1)|),
// i in [0,255]. Scan init = ones_like caps the distance at 1.0.
// Closed form: nearest level of the uniform grid on [-1,1], step 1/127.5:
//   r = clamp(rint((x+1)*127.5), 0, 255);  dist = min(1, |x - (r/127.5 - 1)|)
//
// Round 4 -> 5: stage-1 grid sized so each thread does exactly ONE unrolled
// iteration (8 independent dwordx4 loads, block-local stride, 32 KB span per
// block). 4096 blocks = 16/CU smooths ramp-down vs round 4's 1024 blocks
// running 4-iteration grid-stride loops.

#define BLOCK  256
#define UNROLL 8

__device__ __forceinline__ float qdist(float x) {
    const float INV_D = 127.5f;
    const float D     = 1.0f / 127.5f;
    float r = rintf(__builtin_fmaf(x, INV_D, INV_D)); // (x+1)*127.5
    r = fminf(fmaxf(r, 0.0f), 255.0f);                // v_med3
    float lv = __builtin_fmaf(r, D, -1.0f);
    return fminf(fabsf(x - lv), 1.0f);                // scan init = 1 caps min
}

__device__ __forceinline__ float qdist4(float4 v) {
    return (qdist(v.x) + qdist(v.y)) + (qdist(v.z) + qdist(v.w));
}

__global__ __launch_bounds__(BLOCK) void ql_partial_kernel(
    const float4* __restrict__ in4, int n4,
    const float* __restrict__ in_tail, int ntail,
    float* __restrict__ partial)
{
    // Block-local tiling: block b owns [b*BLOCK*UNROLL, (b+1)*BLOCK*UNROLL)
    // float4s; thread t loads t + u*BLOCK (u = 0..7), all 8 issued together.
    const int base = blockIdx.x * (BLOCK * UNROLL) + threadIdx.x;

    float a[UNROLL];
    #pragma unroll
    for (int u = 0; u < UNROLL; ++u) a[u] = 0.0f;

    if (base + (UNROLL - 1) * BLOCK < n4) {          // fast path: all in bounds
        float4 v[UNROLL];
        #pragma unroll
        for (int u = 0; u < UNROLL; ++u) v[u] = in4[base + u * BLOCK];
        #pragma unroll
        for (int u = 0; u < UNROLL; ++u) a[u] += qdist4(v[u]);
    } else {                                          // edge block
        #pragma unroll
        for (int u = 0; u < UNROLL; ++u) {
            int i = base + u * BLOCK;
            if (i < n4) a[u] += qdist4(in4[i]);
        }
    }

    // scalar tail (n not divisible by 4), first ntail threads of block 0
    if (blockIdx.x == 0 && threadIdx.x < ntail) a[0] += qdist(in_tail[threadIdx.x]);

    float acc = 0.0f;
    #pragma unroll
    for (int u = 0; u < UNROLL; ++u) acc += a[u];

    #pragma unroll
    for (int off = 32; off > 0; off >>= 1)
        acc += __shfl_down(acc, off, 64);

    __shared__ float smem[BLOCK / 64];
    int lane = threadIdx.x & 63;
    int wid  = threadIdx.x >> 6;
    if (lane == 0) smem[wid] = acc;
    __syncthreads();

    if (threadIdx.x == 0) {
        float s = 0.0f;
        #pragma unroll
        for (int w = 0; w < BLOCK / 64; ++w) s += smem[w];
        partial[blockIdx.x] = s;   // plain store, no atomics
    }
}

__global__ __launch_bounds__(BLOCK) void ql_final_kernel(
    const float* __restrict__ partial, int np, float* __restrict__ out)
{
    float acc = 0.0f;
    for (int i = threadIdx.x; i < np; i += BLOCK) acc += partial[i];

    #pragma unroll
    for (int off = 32; off > 0; off >>= 1)
        acc += __shfl_down(acc, off, 64);

    __shared__ float smem[BLOCK / 64];
    int lane = threadIdx.x & 63;
    int wid  = threadIdx.x >> 6;
    if (lane == 0) smem[wid] = acc;
    __syncthreads();

    if (threadIdx.x == 0) {
        float s = 0.0f;
        #pragma unroll
        for (int w = 0; w < BLOCK / 64; ++w) s += smem[w];
        out[0] = s;                // overwrites poison; no memset needed
    }
}

extern "C" void kernel_launch(void* const* d_in, const int* in_sizes, int n_in,
                              void* d_out, int out_size, void* d_ws, size_t ws_size,
                              hipStream_t stream) {
    const float* x = (const float*)d_in[0];
    float* out     = (float*)d_out;
    float* partial = (float*)d_ws;
    int n = in_sizes[0];

    int n4    = n >> 2;
    int ntail = n & 3;
    const float* tail = x + (n4 << 2);

    int grid = (n4 + BLOCK * UNROLL - 1) / (BLOCK * UNROLL);   // 4096 for n4=8M
    int maxp = (int)(ws_size / sizeof(float));
    if (grid > maxp) grid = maxp;        // safety: partials must fit d_ws
    if (grid < 1) grid = 1;

    ql_partial_kernel<<<grid, BLOCK, 0, stream>>>(
        (const float4*)x, n4, tail, ntail, partial);
    ql_final_kernel<<<1, BLOCK, 0, stream>>>(partial, grid, out);
}

// Round 6
// 26.123 us; speedup vs baseline: 1.9737x; 1.1508x over previous
//
#include <hip/hip_runtime.h>

// QuantizationLoss: sum over all elements of min(1, min_i |x - (i/127.5 - 1)|),
// i in [0,255]. Scan init = ones_like caps the distance at 1.0.
// Closed form: nearest level of the uniform grid on [-1,1], step 1/127.5:
//   r = clamp(rint((x+1)*127.5), 0, 255);  dist = min(1, |x - (r/127.5 - 1)|)
//
// Round 5 -> 6: non-temporal (streaming) loads for the single-use 134 MB
// input (skips L2 allocation); BLOCK 256 -> 512 halves partial count and
// workgroup dispatch count; stage-2 widened to 1024 threads.

#define BLOCK  512
#define UNROLL 8

typedef float vfloat4 __attribute__((ext_vector_type(4)));

__device__ __forceinline__ float qdist(float x) {
    const float INV_D = 127.5f;
    const float D     = 1.0f / 127.5f;
    float r = rintf(__builtin_fmaf(x, INV_D, INV_D)); // (x+1)*127.5
    r = fminf(fmaxf(r, 0.0f), 255.0f);                // v_med3
    float lv = __builtin_fmaf(r, D, -1.0f);
    return fminf(fabsf(x - lv), 1.0f);                // scan init = 1 caps min
}

__device__ __forceinline__ float qdist4(vfloat4 v) {
    return (qdist(v.x) + qdist(v.y)) + (qdist(v.z) + qdist(v.w));
}

__global__ __launch_bounds__(BLOCK) void ql_partial_kernel(
    const vfloat4* __restrict__ in4, int n4,
    const float* __restrict__ in_tail, int ntail,
    float* __restrict__ partial)
{
    // Block b owns [b*BLOCK*UNROLL, (b+1)*BLOCK*UNROLL) float4s; thread t
    // loads t + u*BLOCK (u = 0..7), all 8 issued together, non-temporal.
    const int base = blockIdx.x * (BLOCK * UNROLL) + threadIdx.x;

    float a[UNROLL];
    #pragma unroll
    for (int u = 0; u < UNROLL; ++u) a[u] = 0.0f;

    if (base + (UNROLL - 1) * BLOCK < n4) {          // fast path: all in bounds
        vfloat4 v[UNROLL];
        #pragma unroll
        for (int u = 0; u < UNROLL; ++u)
            v[u] = __builtin_nontemporal_load(&in4[base + u * BLOCK]);
        #pragma unroll
        for (int u = 0; u < UNROLL; ++u) a[u] += qdist4(v[u]);
    } else {                                          // edge block
        #pragma unroll
        for (int u = 0; u < UNROLL; ++u) {
            int i = base + u * BLOCK;
            if (i < n4) a[u] += qdist4(__builtin_nontemporal_load(&in4[i]));
        }
    }

    // scalar tail (n not divisible by 4), first ntail threads of block 0
    if (blockIdx.x == 0 && threadIdx.x < ntail) a[0] += qdist(in_tail[threadIdx.x]);

    float acc = 0.0f;
    #pragma unroll
    for (int u = 0; u < UNROLL; ++u) acc += a[u];

    #pragma unroll
    for (int off = 32; off > 0; off >>= 1)
        acc += __shfl_down(acc, off, 64);

    __shared__ float smem[BLOCK / 64];
    int lane = threadIdx.x & 63;
    int wid  = threadIdx.x >> 6;
    if (lane == 0) smem[wid] = acc;
    __syncthreads();

    if (threadIdx.x == 0) {
        float s = 0.0f;
        #pragma unroll
        for (int w = 0; w < BLOCK / 64; ++w) s += smem[w];
        partial[blockIdx.x] = s;   // plain store, no atomics
    }
}

#define FBLOCK 1024
__global__ __launch_bounds__(FBLOCK) void ql_final_kernel(
    const float* __restrict__ partial, int np, float* __restrict__ out)
{
    float acc = 0.0f;
    for (int i = threadIdx.x; i < np; i += FBLOCK) acc += partial[i];

    #pragma unroll
    for (int off = 32; off > 0; off >>= 1)
        acc += __shfl_down(acc, off, 64);

    __shared__ float smem[FBLOCK / 64];
    int lane = threadIdx.x & 63;
    int wid  = threadIdx.x >> 6;
    if (lane == 0) smem[wid] = acc;
    __syncthreads();

    if (threadIdx.x == 0) {
        float s = 0.0f;
        #pragma unroll
        for (int w = 0; w < FBLOCK / 64; ++w) s += smem[w];
        out[0] = s;                // overwrites poison; no memset needed
    }
}

extern "C" void kernel_launch(void* const* d_in, const int* in_sizes, int n_in,
                              void* d_out, int out_size, void* d_ws, size_t ws_size,
                              hipStream_t stream) {
    const float* x = (const float*)d_in[0];
    float* out     = (float*)d_out;
    float* partial = (float*)d_ws;
    int n = in_sizes[0];

    int n4    = n >> 2;
    int ntail = n & 3;
    const float* tail = x + (n4 << 2);

    int grid = (n4 + BLOCK * UNROLL - 1) / (BLOCK * UNROLL);   // 2048 for n4=8M
    int maxp = (int)(ws_size / sizeof(float));
    if (grid > maxp) grid = maxp;        // safety: partials must fit d_ws
    if (grid < 1) grid = 1;

    ql_partial_kernel<<<grid, BLOCK, 0, stream>>>(
        (const vfloat4*)x, n4, tail, ntail, partial);
    ql_final_kernel<<<1, FBLOCK, 0, stream>>>(partial, grid, out);
}